// Round 4
// baseline (92.694 us; speedup 1.0000x reference)
//
#include <hip/hip_runtime.h>
#include <math.h>

// StructureLoss: pred [16,2,512,512] f32, mask [16,512,512] f32 -> scalar f32
// loss = mean_b( wbce_b + wiou_b ), weit = 1 + 5*|boxavg31(m) - m|
//
// R9 geometry: 128x64 tiles (TH=128), 512 blocks = exactly 2/CU x 1 round.
//  - halo overfetch 2.16x -> 1.81x (mask traffic 36 -> 30 MB)
//  - vertical: 376 balanced tasks, 62-row windows -> 32 outputs each
//    (1/3 less vertical LDS work); no keep[] arrays (re-read LDS, cheap)
//  - horizontal: 16 px/thread, 31-tap startup amortized 2x
//  - staging: 8 independent float4 loads batched before 8 ds_write_b128
//    (explicit MLP; R7 showed the compiler otherwise serializes at VGPR=36)
//  - LDS 60.7 KB: raw [158][96]; vsum [128][95] aliased over it after a
//    barrier. All LDS patterns <=2-way (free); mv b128 re-read rotated by
//    (k+ch)&3 to dodge a 4-way.
#define B_   16
#define H_   512
#define W_   512
#define HW_  (H_ * W_)
#define MU_  5.0f
#define KK_INV (1.0f / 961.0f)
#define TH   128
#define TW   64
#define NTHR 512
#define NROWS 158              // TH + 30
#define RSTRIDE 96             // raw row stride (floats), 16B-aligned rows
#define VSTRIDE 95             // vsum stride: odd -> scalar reads <=2-way
#define NQ 24                  // float4s per raw row
#define NSTG (NROWS * NQ)      // 3792 staging tasks
#define NVTASK 376             // 4 row-groups(32) x 94 halo cols
#define NBLK 512               // 8 x 4 x 16

__device__ __align__(16) float g_part[NBLK * 4];

__global__ __launch_bounds__(NTHR, 4) void structure_loss_tile(
    const float* __restrict__ pred,     // [B,2,H,W]
    const float* __restrict__ mask)     // [B,H,W]
{
    __shared__ float smem[NROWS * RSTRIDE];   // 60,672 B; vsum aliased after P3
    __shared__ float wsum[8][4];

    const int tid = threadIdx.x;
    const int b   = blockIdx.z;
    const int r0  = blockIdx.y * TH;
    const int c0  = blockIdx.x * TW;
    const int blk = (blockIdx.z * gridDim.y + blockIdx.y) * gridDim.x + blockIdx.x;

    const float* mb = mask + (size_t)b * HW_;
    const float* pb = pred + ((size_t)b * 2 + 1) * HW_;   // channel-1 logits

    // ---- Horizontal-phase coordinates: 16 output px per thread ----
    const int r   = tid >> 2;           // 0..127
    const int ch  = tid & 3;            // 0..3
    const int gr  = r0 + r;
    const int gcb = c0 + ch * 16;       // 64B-aligned

    // ---- P1a: pred prefetch (4 float4), issued with the stage loads ----
    const float4* p4 = (const float4*)(pb + gr * W_ + gcb);
    const float4 pq0 = p4[0], pq1 = p4[1], pq2 = p4[2], pq3 = p4[3];

    // ---- P1b: stage raw mask halo: 158 rows x 24 float4 = 3792 tasks ----
    {
        const int gyb = r0 - 15;
        const int gxb = c0 - 16;
        float4 vbuf[8];
        int    laddr[8];
        #pragma unroll
        for (int rnd = 0; rnd < 8; ++rnd) {
            const int task = tid + rnd * NTHR;
            float4 v = make_float4(0.f, 0.f, 0.f, 0.f);
            int la = -1;
            if (task < NSTG) {
                const int row = task / NQ;
                const int q   = task - row * NQ;
                const int gy  = gyb + row;
                const int gx  = gxb + q * 4;    // multiple of 4 -> f4-granular OOB
                if (((unsigned)gy < (unsigned)H_) & ((unsigned)gx < (unsigned)W_))
                    v = *(const float4*)(mb + gy * W_ + gx);
                la = row * RSTRIDE + q * 4;
            }
            vbuf[rnd] = v;
            laddr[rnd] = la;
        }
        #pragma unroll
        for (int rnd = 0; rnd < 8; ++rnd) {
            if (laddr[rnd] >= 0)
                *(float4*)(&smem[laddr[rnd]]) = vbuf[rnd];
        }
    }
    // keep pred values resident (don't let the loads sink past the barriers)
    asm volatile("" :: "v"(pq0.x), "v"(pq0.y), "v"(pq0.z), "v"(pq0.w),
                       "v"(pq1.x), "v"(pq1.y), "v"(pq1.z), "v"(pq1.w),
                       "v"(pq2.x), "v"(pq2.y), "v"(pq2.z), "v"(pq2.w),
                       "v"(pq3.x), "v"(pq3.y), "v"(pq3.z), "v"(pq3.w));
    __syncthreads();

    // ---- P2: mask row for elementwise (from staged raw) + vertical sums ----
    float mv[16];
    {
        const int mbase = (r + 15) * RSTRIDE + ch * 16 + 16;
        #pragma unroll
        for (int k = 0; k < 4; ++k) {
            const int kk = (k + ch) & 3;     // rotation: dodge 4-way b128 conflict
            const float4 t = *(const float4*)(&smem[mbase + 4 * kk]);
            mv[kk*4+0] = t.x; mv[kk*4+1] = t.y; mv[kk*4+2] = t.z; mv[kk*4+3] = t.w;
        }
    }

    float vs[32];
    int rg = 0, cc = 0;
    if (tid < NVTASK) {
        rg = tid / 94;                       // 0..3
        cc = tid - rg * 94;                  // 0..93
        const float* col = &smem[(rg * 32) * RSTRIDE + cc + 1];
        float s = 0.0f;
        #pragma unroll
        for (int d = 0; d < 31; ++d)
            s += col[d * RSTRIDE];
        vs[0] = s;
        #pragma unroll
        for (int i = 1; i < 32; ++i) {
            s += col[(i + 30) * RSTRIDE] - col[(i - 1) * RSTRIDE];
            vs[i] = s;
        }
    }
    __syncthreads();

    // ---- P3: write vsum [128][95] over the raw region (alias, post-barrier) ----
    if (tid < NVTASK) {
        float* vout = &smem[(rg * 32) * VSTRIDE + cc];
        #pragma unroll
        for (int i = 0; i < 32; ++i)
            vout[i * VSTRIDE] = vs[i];
    }
    __syncthreads();

    // ---- P4: horizontal 31-tap slide fused with elementwise math ----
    const int base = r * VSTRIDE + ch * 16;
    float s = 0.0f;
    #pragma unroll
    for (int d = 0; d < 31; ++d)
        s += smem[base + d];

    float pv[16] = { pq0.x, pq0.y, pq0.z, pq0.w,  pq1.x, pq1.y, pq1.z, pq1.w,
                     pq2.x, pq2.y, pq2.z, pq2.w,  pq3.x, pq3.y, pq3.z, pq3.w };

    float s_w = 0.0f, s_wb = 0.0f, s_in = 0.0f, s_un = 0.0f;
    #pragma unroll
    for (int j = 0; j < 16; ++j) {
        const float avg = s * KK_INV;
        const float m = mv[j];
        const float p = pv[j];

        const float weit = 1.0f + MU_ * fabsf(avg - m);
        // e = exp(-|p|); bce = max(p,0) - p*m + log(1+e); sigmoid = (p>=0?1:e)/(1+e)
        const float e    = __expf(-fabsf(p));
        const float inv  = __builtin_amdgcn_rcpf(1.0f + e);
        const float bce  = fmaxf(p, 0.0f) - p * m + __logf(1.0f + e);
        const float ps   = (p >= 0.0f ? 1.0f : e) * inv;

        s_w  += weit;
        s_wb += weit * bce;
        s_in += ps * m * weit;
        s_un += (ps + m) * weit;

        if (j < 15)
            s += smem[base + 31 + j] - smem[base + j];
    }

    // ---- block reduction: wave shuffle -> LDS -> one store per component ----
    const int lane = tid & 63;
    const int wid  = tid >> 6;          // 0..7
    float vals[4] = { s_w, s_wb, s_in, s_un };
    #pragma unroll
    for (int q = 0; q < 4; ++q) {
        float v = vals[q];
        #pragma unroll
        for (int off = 32; off > 0; off >>= 1)
            v += __shfl_down(v, off);
        if (lane == 0) wsum[wid][q] = v;
    }
    __syncthreads();
    if (tid < 4) {
        float tot = 0.0f;
        #pragma unroll
        for (int w = 0; w < 8; ++w) tot += wsum[w][tid];
        g_part[blk * 4 + tid] = tot;    // unconditional write -> no memset needed
    }
}

__global__ void structure_loss_final(float* __restrict__ out)
{
    // 64 threads; 4 threads per batch (32 blocks/batch), 8 float4 each.
    const int t = threadIdx.x;
    const float4* p4 = (const float4*)g_part;    // one float4 per block
    float4 v = make_float4(0.f, 0.f, 0.f, 0.f);
    #pragma unroll
    for (int j = 0; j < 8; ++j) {
        const float4 q = p4[t * 8 + j];
        v.x += q.x; v.y += q.y; v.z += q.z; v.w += q.w;
    }
    #pragma unroll
    for (int off = 2; off > 0; off >>= 1) {
        v.x += __shfl_down(v.x, off);
        v.y += __shfl_down(v.y, off);
        v.z += __shfl_down(v.z, off);
        v.w += __shfl_down(v.w, off);
    }
    float loss = 0.0f;
    if ((t & 3) == 0) {
        const float sw = v.x, swb = v.y, inter = v.z, uni = v.w;
        loss = swb / sw + 1.0f - (inter + 1.0f) / (uni - inter + 1.0f);
    }
    #pragma unroll
    for (int off = 32; off >= 4; off >>= 1)
        loss += __shfl_down(loss, off);
    if (t == 0) out[0] = loss * (1.0f / (float)B_);
}

extern "C" void kernel_launch(void* const* d_in, const int* in_sizes, int n_in,
                              void* d_out, int out_size, void* d_ws, size_t ws_size,
                              hipStream_t stream) {
    const float* pred = (const float*)d_in[0];
    const float* mask = (const float*)d_in[1];
    float* out = (float*)d_out;
    (void)d_ws; (void)ws_size;          // workspace deliberately untouched

    dim3 grid(W_ / TW, H_ / TH, B_);    // 8 x 4 x 16 = 512 blocks
    structure_loss_tile<<<grid, NTHR, 0, stream>>>(pred, mask);
    structure_loss_final<<<1, 64, 0, stream>>>(out);
}

// Round 5
// 90.151 us; speedup vs baseline: 1.0282x; 1.0282x over previous
//
#include <hip/hip_runtime.h>
#include <math.h>

// StructureLoss: pred [16,2,512,512] f32, mask [16,512,512] f32 -> scalar f32
// loss = mean_b( wbce_b + wiou_b ), weit = 1 + 5*|boxavg31(m) - m|
//
// R10 = R9 + two derived fixes:
//  1. RSTRIDE 96 -> 100. 96 floats = 384 B == 0 mod 32 banks, so any
//     fixed-column read across rows (the mv b128 re-read, 16 lanes/ch) was a
//     16-way bank conflict (~64cyc/instr). 100 = 4 mod 32 spreads rows over
//     8 bank-groups; with the (k+ch)&3 rotation the mv read is 2-way = free.
//  2. XCD-aware tile swizzle (bijective, 512 = 8*64): XCD k owns tiles
//     [64k,64k+64) = 2 whole batches, so the 13 MB of mask-halo re-reads
//     (1.81x overfetch) hit that XCD's private L2 (1 MB slice << 4 MiB)
//     instead of HBM.
// Geometry unchanged from R9: 128x64 tiles, 512 thr, 512 blocks = 2/CU,
// batched float4 staging, vertical 62-row windows -> 32 outputs, LDS alias
// for vsum, 16 px/thread horizontal+elementwise, two-kernel finish.
#define B_   16
#define H_   512
#define W_   512
#define HW_  (H_ * W_)
#define MU_  5.0f
#define KK_INV (1.0f / 961.0f)
#define TH   128
#define TW   64
#define NTHR 512
#define NROWS 158              // TH + 30
#define RSTRIDE 100            // raw row stride: 16B-aligned, 4 mod 32 banks
#define VSTRIDE 95             // vsum stride: odd -> scalar reads <=2-way
#define NQ 24                  // float4s staged per raw row (96 cols, 94 used)
#define NSTG (NROWS * NQ)      // 3792 staging tasks
#define NVTASK 376             // 4 row-groups(32) x 94 halo cols
#define NBLK 512               // 8 x 4 x 16

__device__ __align__(16) float g_part[NBLK * 4];

__global__ __launch_bounds__(NTHR, 4) void structure_loss_tile(
    const float* __restrict__ pred,     // [B,2,H,W]
    const float* __restrict__ mask)     // [B,H,W]
{
    __shared__ float smem[NROWS * RSTRIDE];   // 63,200 B; vsum aliased after P3
    __shared__ float wsum[8][4];

    const int tid = threadIdx.x;

    // ---- XCD-aware tile assignment (bijective: 512 = 8 XCDs x 64) ----
    // HW round-robins dispatch-linear bid across XCDs (bid%8). Remap so each
    // XCD sees 64 consecutive tiles = 2 complete batches -> halo re-reads
    // are L2-local.
    const int bid = (blockIdx.z * gridDim.y + blockIdx.y) * gridDim.x + blockIdx.x;
    const int t   = (bid & 7) * 64 + (bid >> 3);
    const int tx  = t & 7;
    const int ty  = (t >> 3) & 3;
    const int b   = t >> 5;
    const int r0  = ty * TH;
    const int c0  = tx * TW;
    const int blk = t;                  // g_part layout: tile-index order

    const float* mb = mask + (size_t)b * HW_;
    const float* pb = pred + ((size_t)b * 2 + 1) * HW_;   // channel-1 logits

    // ---- Horizontal-phase coordinates: 16 output px per thread ----
    const int r   = tid >> 2;           // 0..127
    const int ch  = tid & 3;            // 0..3
    const int gr  = r0 + r;
    const int gcb = c0 + ch * 16;       // 64B-aligned

    // ---- P1a: pred prefetch (4 float4), issued with the stage loads ----
    const float4* p4 = (const float4*)(pb + gr * W_ + gcb);
    const float4 pq0 = p4[0], pq1 = p4[1], pq2 = p4[2], pq3 = p4[3];

    // ---- P1b: stage raw mask halo: 158 rows x 24 float4 = 3792 tasks ----
    {
        const int gyb = r0 - 15;
        const int gxb = c0 - 16;
        float4 vbuf[8];
        int    laddr[8];
        #pragma unroll
        for (int rnd = 0; rnd < 8; ++rnd) {
            const int task = tid + rnd * NTHR;
            float4 v = make_float4(0.f, 0.f, 0.f, 0.f);
            int la = -1;
            if (task < NSTG) {
                const int row = task / NQ;
                const int q   = task - row * NQ;
                const int gy  = gyb + row;
                const int gx  = gxb + q * 4;    // multiple of 4 -> f4-granular OOB
                if (((unsigned)gy < (unsigned)H_) & ((unsigned)gx < (unsigned)W_))
                    v = *(const float4*)(mb + gy * W_ + gx);
                la = row * RSTRIDE + q * 4;
            }
            vbuf[rnd] = v;
            laddr[rnd] = la;
        }
        #pragma unroll
        for (int rnd = 0; rnd < 8; ++rnd) {
            if (laddr[rnd] >= 0)
                *(float4*)(&smem[laddr[rnd]]) = vbuf[rnd];
        }
    }
    // keep pred values resident (don't let the loads sink past the barriers)
    asm volatile("" :: "v"(pq0.x), "v"(pq0.y), "v"(pq0.z), "v"(pq0.w),
                       "v"(pq1.x), "v"(pq1.y), "v"(pq1.z), "v"(pq1.w),
                       "v"(pq2.x), "v"(pq2.y), "v"(pq2.z), "v"(pq2.w),
                       "v"(pq3.x), "v"(pq3.y), "v"(pq3.z), "v"(pq3.w));
    __syncthreads();

    // ---- P2: mask row for elementwise (from staged raw) + vertical sums ----
    float mv[16];
    {
        const int mbase = (r + 15) * RSTRIDE + ch * 16 + 16;
        #pragma unroll
        for (int k = 0; k < 4; ++k) {
            const int kk = (k + ch) & 3;     // rotation: 2-way (free) with RSTRIDE=100
            const float4 tq = *(const float4*)(&smem[mbase + 4 * kk]);
            mv[kk*4+0] = tq.x; mv[kk*4+1] = tq.y; mv[kk*4+2] = tq.z; mv[kk*4+3] = tq.w;
        }
    }

    float vs[32];
    int rg = 0, cc = 0;
    if (tid < NVTASK) {
        rg = tid / 94;                       // 0..3
        cc = tid - rg * 94;                  // 0..93
        const float* col = &smem[(rg * 32) * RSTRIDE + cc + 1];
        float s = 0.0f;
        #pragma unroll
        for (int d = 0; d < 31; ++d)
            s += col[d * RSTRIDE];
        vs[0] = s;
        #pragma unroll
        for (int i = 1; i < 32; ++i) {
            s += col[(i + 30) * RSTRIDE] - col[(i - 1) * RSTRIDE];
            vs[i] = s;
        }
    }
    __syncthreads();

    // ---- P3: write vsum [128][95] over the raw region (alias, post-barrier) ----
    if (tid < NVTASK) {
        float* vout = &smem[(rg * 32) * VSTRIDE + cc];
        #pragma unroll
        for (int i = 0; i < 32; ++i)
            vout[i * VSTRIDE] = vs[i];
    }
    __syncthreads();

    // ---- P4: horizontal 31-tap slide fused with elementwise math ----
    const int base = r * VSTRIDE + ch * 16;
    float s = 0.0f;
    #pragma unroll
    for (int d = 0; d < 31; ++d)
        s += smem[base + d];

    float pv[16] = { pq0.x, pq0.y, pq0.z, pq0.w,  pq1.x, pq1.y, pq1.z, pq1.w,
                     pq2.x, pq2.y, pq2.z, pq2.w,  pq3.x, pq3.y, pq3.z, pq3.w };

    float s_w = 0.0f, s_wb = 0.0f, s_in = 0.0f, s_un = 0.0f;
    #pragma unroll
    for (int j = 0; j < 16; ++j) {
        const float avg = s * KK_INV;
        const float m = mv[j];
        const float p = pv[j];

        const float weit = 1.0f + MU_ * fabsf(avg - m);
        // e = exp(-|p|); bce = max(p,0) - p*m + log(1+e); sigmoid = (p>=0?1:e)/(1+e)
        const float e    = __expf(-fabsf(p));
        const float inv  = __builtin_amdgcn_rcpf(1.0f + e);
        const float bce  = fmaxf(p, 0.0f) - p * m + __logf(1.0f + e);
        const float ps   = (p >= 0.0f ? 1.0f : e) * inv;

        s_w  += weit;
        s_wb += weit * bce;
        s_in += ps * m * weit;
        s_un += (ps + m) * weit;

        if (j < 15)
            s += smem[base + 31 + j] - smem[base + j];
    }

    // ---- block reduction: wave shuffle -> LDS -> one store per component ----
    const int lane = tid & 63;
    const int wid  = tid >> 6;          // 0..7
    float vals[4] = { s_w, s_wb, s_in, s_un };
    #pragma unroll
    for (int q = 0; q < 4; ++q) {
        float v = vals[q];
        #pragma unroll
        for (int off = 32; off > 0; off >>= 1)
            v += __shfl_down(v, off);
        if (lane == 0) wsum[wid][q] = v;
    }
    __syncthreads();
    if (tid < 4) {
        float tot = 0.0f;
        #pragma unroll
        for (int w = 0; w < 8; ++w) tot += wsum[w][tid];
        g_part[blk * 4 + tid] = tot;    // unconditional write -> no memset needed
    }
}

__global__ void structure_loss_final(float* __restrict__ out)
{
    // 64 threads; 4 threads per batch (32 blocks/batch), 8 float4 each.
    const int t = threadIdx.x;
    const float4* p4 = (const float4*)g_part;    // one float4 per block
    float4 v = make_float4(0.f, 0.f, 0.f, 0.f);
    #pragma unroll
    for (int j = 0; j < 8; ++j) {
        const float4 q = p4[t * 8 + j];
        v.x += q.x; v.y += q.y; v.z += q.z; v.w += q.w;
    }
    #pragma unroll
    for (int off = 2; off > 0; off >>= 1) {
        v.x += __shfl_down(v.x, off);
        v.y += __shfl_down(v.y, off);
        v.z += __shfl_down(v.z, off);
        v.w += __shfl_down(v.w, off);
    }
    float loss = 0.0f;
    if ((t & 3) == 0) {
        const float sw = v.x, swb = v.y, inter = v.z, uni = v.w;
        loss = swb / sw + 1.0f - (inter + 1.0f) / (uni - inter + 1.0f);
    }
    #pragma unroll
    for (int off = 32; off >= 4; off >>= 1)
        loss += __shfl_down(loss, off);
    if (t == 0) out[0] = loss * (1.0f / (float)B_);
}

extern "C" void kernel_launch(void* const* d_in, const int* in_sizes, int n_in,
                              void* d_out, int out_size, void* d_ws, size_t ws_size,
                              hipStream_t stream) {
    const float* pred = (const float*)d_in[0];
    const float* mask = (const float*)d_in[1];
    float* out = (float*)d_out;
    (void)d_ws; (void)ws_size;          // workspace deliberately untouched

    dim3 grid(W_ / TW, H_ / TH, B_);    // 8 x 4 x 16 = 512 blocks
    structure_loss_tile<<<grid, NTHR, 0, stream>>>(pred, mask);
    structure_loss_final<<<1, 64, 0, stream>>>(out);
}